// Round 2
// baseline (592.149 us; speedup 1.0000x reference)
//
#include <hip/hip_runtime.h>

// LePEAttention fused: B=16, H=W=64, C=384, HEADS=12, hd=32, IDX=0.
// K1 (k_fused): block = strip (b,w). LePE store -> per-wave QKV via MFMA with
//   A-frags held in regs (from fp32 x) -> per-head attention -> RMW afused.
// K2 (k_gemm<384,true>): proj GEMM + bias -> fp32 out. (unchanged, proven)
// MFMA layouts (HW-verified): A[m=lane&15][k=quad*8+j]; B mirrored;
//   C/D: col=lane&15, row=quad*4+reg.

typedef _Float16 f16;
typedef _Float16 f16x8 __attribute__((ext_vector_type(8)));
typedef _Float16 f16x4 __attribute__((ext_vector_type(4)));
typedef float    f32x4 __attribute__((ext_vector_type(4)));

__device__ __forceinline__ f32x4 mfma_16x16x32(f16x8 a, f16x8 b, f32x4 c) {
  return __builtin_amdgcn_mfma_f32_16x16x32_f16(a, b, c, 0, 0, 0);
}

// ---------------- fp32 -> fp16 convert (8 elems/thread) ----------------
__global__ __launch_bounds__(256) void k_cvt(const float* __restrict__ src,
                                             f16* __restrict__ dst, int n8) {
  int i = blockIdx.x * 256 + threadIdx.x;
  if (i >= n8) return;
  const f32x4* s4 = (const f32x4*)src;
  f32x4 a = s4[2 * i], b = s4[2 * i + 1];
  f16x8 o;
#pragma unroll
  for (int j = 0; j < 4; ++j) { o[j] = (f16)a[j]; o[4 + j] = (f16)b[j]; }
  *(f16x8*)&dst[(long)i * 8] = o;
}

// ---------------- fused LePE + QKV + attention ----------------
// 256 threads = 4 waves: wave = (nh<<1)|mh ; mh = M-half (rows 32*mh..+32),
// nh = head group (heads 6*nh..+5).
__global__ __launch_bounds__(256, 2) void k_fused(const float* __restrict__ x,
                                                  const f16* __restrict__ w16,
                                                  const float* __restrict__ lw,
                                                  const float* __restrict__ lb,
                                                  f16* __restrict__ afused) {
  // per head-group LDS (halfs): qs@0 (64x40), ks@2560 (64x40), vt@5120 (32x72),
  // ps@7424 (64x72), obuf@12032 (64x40). total 14592 h x2 groups = 58368 B.
  __shared__ f16 shp[2][14592];
  const int tid = threadIdx.x;
  const int lane = tid & 63;
  const int wave = tid >> 6;
  const int mh = wave & 1, nh = wave >> 1;
  const int ln = lane & 15, quad = lane >> 4, q8 = quad * 8;
  const int b = blockIdx.x >> 6, w = blockIdx.x & 63;

  f16* qs = shp[nh];
  f16* ks = shp[nh] + 2560;
  f16* vt = shp[nh] + 5120;
  f16* ps = shp[nh] + 7424;
  f16* obuf = shp[nh] + 12032;

  // ---- Phase 1: LePE depthwise 3x3 (fp32) -> STORE afused rows w*64+l ----
  {
    const float* xb = x + (long)b * 4096 * 384;
    const int l = lane;
    f16* arow = afused + ((long)(b * 4096 + w * 64 + l)) * 384;
#pragma unroll
    for (int it = 0; it < 12; ++it) {
      int c0 = (it * 4 + wave) * 8;
      float a8[8];
#pragma unroll
      for (int cc = 0; cc < 8; ++cc) a8[cc] = lb[c0 + cc];
#pragma unroll
      for (int ky = 0; ky < 3; ++ky) {
        int hh2 = w + ky - 1;
        if (hh2 < 0 || hh2 > 63) continue;
#pragma unroll
        for (int kx = 0; kx < 3; ++kx) {
          int ww2 = l + kx - 1;
          if (ww2 < 0 || ww2 > 63) continue;
          const float* p = xb + ((hh2 << 6) + ww2) * 384 + c0;
          float4 u = *(const float4*)p;
          float4 v2 = *(const float4*)(p + 4);
#pragma unroll
          for (int cc = 0; cc < 4; ++cc) {
            a8[cc] += u.x * 0.f;  // (placeholder removed below)
          }
          // accumulate taps
#pragma unroll
          for (int cc = 0; cc < 4; ++cc) {
            float wv0 = lw[(c0 + cc) * 9 + ky * 3 + kx];
            float wv1 = lw[(c0 + 4 + cc) * 9 + ky * 3 + kx];
            float xv0 = (cc == 0) ? u.x : (cc == 1) ? u.y : (cc == 2) ? u.z : u.w;
            float xv1 = (cc == 0) ? v2.x : (cc == 1) ? v2.y : (cc == 2) ? v2.z : v2.w;
            a8[cc] += xv0 * wv0;
            a8[4 + cc] += xv1 * wv1;
          }
        }
      }
      f16x8 o;
#pragma unroll
      for (int cc = 0; cc < 8; ++cc) o[cc] = (f16)a8[cc];
      *(f16x8*)&arow[c0] = o;
    }
  }
  __syncthreads();  // lepe stores visible before attention RMW

  // ---- Phase 2: A-fragments (x strip column w) fp32 -> f16 regs ----
  // row m -> token m*64 + w ; afr[s][i] = A[m=32mh+16i+ln][k=s*32+q8..+8]
  f16x8 afr[12][2];
  {
    const float* xcol = x + ((long)(b * 4096) + w) * 384;
#pragma unroll
    for (int s = 0; s < 12; ++s)
#pragma unroll
      for (int i = 0; i < 2; ++i) {
        const float* p = xcol + (long)(mh * 32 + i * 16 + ln) * 24576 + s * 32 + q8;
        float4 u = *(const float4*)p;
        float4 v2 = *(const float4*)(p + 4);
        f16x8 t;
        t[0] = (f16)u.x; t[1] = (f16)u.y; t[2] = (f16)u.z; t[3] = (f16)u.w;
        t[4] = (f16)v2.x; t[5] = (f16)v2.y; t[6] = (f16)v2.z; t[7] = (f16)v2.w;
        afr[s][i] = t;
      }
  }

  const float qscale = 0.17677669529663687f;  // 32^-0.5

  // ---- Phase 3: head loop ----
  for (int h6 = 0; h6 < 6; ++h6) {
    const int hh = nh * 6 + h6;
    // QKV passes: p=0 q, p=1 k, p=2 v. out tile 32(rows) x 32(cols), K=384.
#pragma unroll
    for (int pass = 0; pass < 3; ++pass) {
      f32x4 acc[2][2] = {};
      const f16* wb = w16 + (long)(pass * 384 + hh * 32) * 384;
#pragma unroll
      for (int s = 0; s < 12; ++s) {
        f16x8 bf[2];
#pragma unroll
        for (int j = 0; j < 2; ++j)
          bf[j] = *(const f16x8*)&wb[(long)(j * 16 + ln) * 384 + s * 32 + q8];
#pragma unroll
        for (int i = 0; i < 2; ++i)
#pragma unroll
          for (int j = 0; j < 2; ++j)
            acc[i][j] = mfma_16x16x32(afr[s][i], bf[j], acc[i][j]);
      }
      if (pass == 0) {
#pragma unroll
        for (int i = 0; i < 2; ++i)
#pragma unroll
          for (int j = 0; j < 2; ++j)
#pragma unroll
            for (int r = 0; r < 4; ++r)
              qs[(mh * 32 + i * 16 + quad * 4 + r) * 40 + j * 16 + ln] =
                  (f16)(acc[i][j][r] * qscale);
      } else if (pass == 1) {
#pragma unroll
        for (int i = 0; i < 2; ++i)
#pragma unroll
          for (int j = 0; j < 2; ++j)
#pragma unroll
            for (int r = 0; r < 4; ++r)
              ks[(mh * 32 + i * 16 + quad * 4 + r) * 40 + j * 16 + ln] =
                  (f16)acc[i][j][r];
      } else {
#pragma unroll
        for (int i = 0; i < 2; ++i)
#pragma unroll
          for (int j = 0; j < 2; ++j) {
            f16x4 pk;
            pk[0] = (f16)acc[i][j][0]; pk[1] = (f16)acc[i][j][1];
            pk[2] = (f16)acc[i][j][2]; pk[3] = (f16)acc[i][j][3];
            *(f16x4*)&vt[(j * 16 + ln) * 72 + mh * 32 + i * 16 + quad * 4] = pk;
          }
      }
    }
    __syncthreads();  // B1: q/k/v complete (both M-halves) before S/PV reads

    // S = Q K^T : own 32 rows x 64 cols, K=32 (1 step)
    f16x8 aq[2], bk[4];
#pragma unroll
    for (int i = 0; i < 2; ++i)
      aq[i] = *(const f16x8*)&qs[(mh * 32 + i * 16 + ln) * 40 + q8];
#pragma unroll
    for (int j = 0; j < 4; ++j)
      bk[j] = *(const f16x8*)&ks[(j * 16 + ln) * 40 + q8];
    f32x4 sc[2][4] = {};
#pragma unroll
    for (int i = 0; i < 2; ++i)
#pragma unroll
      for (int j = 0; j < 4; ++j) sc[i][j] = mfma_16x16x32(aq[i], bk[j], sc[i][j]);

    // softmax rows (q pre-scaled); deferred normalization via rs
    float rs[2][4];
#pragma unroll
    for (int i = 0; i < 2; ++i) {
#pragma unroll
      for (int r = 0; r < 4; ++r) {
        float m = -1e30f;
#pragma unroll
        for (int j = 0; j < 4; ++j) m = fmaxf(m, sc[i][j][r]);
#pragma unroll
        for (int off = 1; off < 16; off <<= 1) m = fmaxf(m, __shfl_xor(m, off, 64));
        float sum = 0.f;
#pragma unroll
        for (int j = 0; j < 4; ++j) {
          float p = __expf(sc[i][j][r] - m);
          sc[i][j][r] = p;
          sum += p;
        }
#pragma unroll
        for (int off = 1; off < 16; off <<= 1) sum += __shfl_xor(sum, off, 64);
        rs[i][r] = 1.0f / sum;
      }
    }

    // P -> ps (own rows; same-wave in-order DS makes reads below safe)
#pragma unroll
    for (int i = 0; i < 2; ++i)
#pragma unroll
      for (int j = 0; j < 4; ++j)
#pragma unroll
        for (int r = 0; r < 4; ++r)
          ps[(mh * 32 + i * 16 + quad * 4 + r) * 72 + j * 16 + ln] = (f16)sc[i][j][r];

    // O = P V : own 32 rows x 32 cols, K=64 (2 steps)
    f32x4 oc[2][2] = {};
#pragma unroll
    for (int k2 = 0; k2 < 2; ++k2) {
      f16x8 ap[2], bv[2];
#pragma unroll
      for (int i = 0; i < 2; ++i)
        ap[i] = *(const f16x8*)&ps[(mh * 32 + i * 16 + ln) * 72 + k2 * 32 + q8];
#pragma unroll
      for (int j = 0; j < 2; ++j)
        bv[j] = *(const f16x8*)&vt[(j * 16 + ln) * 72 + k2 * 32 + q8];
#pragma unroll
      for (int i = 0; i < 2; ++i)
#pragma unroll
        for (int j = 0; j < 2; ++j) oc[i][j] = mfma_16x16x32(ap[i], bv[j], oc[i][j]);
    }

    // epilogue: normalize -> obuf (own rows) -> vectorized RMW into afused
#pragma unroll
    for (int i = 0; i < 2; ++i)
#pragma unroll
      for (int j = 0; j < 2; ++j)
#pragma unroll
        for (int r = 0; r < 4; ++r)
          obuf[(mh * 32 + i * 16 + quad * 4 + r) * 40 + j * 16 + ln] =
              (f16)(oc[i][j][r] * rs[i][r]);
    {
      int row = mh * 32 + (lane >> 1), hf = lane & 1;
      f16* gp = afused + ((long)(b * 4096 + w * 64 + row)) * 384 + hh * 32 + hf * 16;
      const f16* ob = &obuf[row * 40 + hf * 16];
      f16x8 o0 = *(const f16x8*)ob, o1 = *(const f16x8*)(ob + 8);
      f16x8 g0 = *(const f16x8*)gp, g1 = *(const f16x8*)(gp + 8);
      g0 = g0 + o0;
      g1 = g1 + o1;
      *(f16x8*)gp = g0;
      *(f16x8*)(gp + 8) = g1;
    }
    __syncthreads();  // B2: protect qs/ks/vt/ps overwrites next head
  }
}

// ---------------- GEMM: C[M x NDIM] = A[M x 384] * Bt[NDIM x 384]^T ----------------
// (unchanged from round 1 — proven) 128x128 tile, BK=64, 4 waves 2x2, 4x4 acc.
template <int NDIM, bool FINAL>
__global__ __launch_bounds__(256) void k_gemm(const f16* __restrict__ A,
                                              const f16* __restrict__ Bt,
                                              const float* __restrict__ bias,
                                              f16* __restrict__ Ch,
                                              float* __restrict__ Cf) {
  constexpr int KD = 384;
  constexpr int LDSP = 72;
  constexpr int NT = NDIM / 128;
  __shared__ f16 As[128 * LDSP];
  __shared__ f16 Bs[128 * LDSP];

  const int tid = threadIdx.x;
  const int lane = tid & 63;
  const int wave = tid >> 6;
  const int wr = wave >> 1, wc = wave & 1;
  const int ln = lane & 15, quad = lane >> 4;
  const int q8 = quad * 8;
  const int mt = blockIdx.x / NT;
  const int nt = blockIdx.x % NT;
  const long m0 = (long)mt * 128;
  const int n0 = nt * 128;

  f32x4 acc[4][4] = {};

  for (int k0 = 0; k0 < KD; k0 += 64) {
#pragma unroll
    for (int r = 0; r < 4; ++r) {
      int flat = r * 256 + tid;
      int row = flat >> 3;
      int kk = (flat & 7) * 8;
      f16x8 av = *(const f16x8*)&A[(m0 + row) * KD + k0 + kk];
      *(f16x8*)&As[row * LDSP + kk] = av;
      f16x8 bv = *(const f16x8*)&Bt[(long)(n0 + row) * KD + k0 + kk];
      *(f16x8*)&Bs[row * LDSP + kk] = bv;
    }
    __syncthreads();
#pragma unroll
    for (int ks = 0; ks < 2; ++ks) {
      f16x8 a[4], b[4];
#pragma unroll
      for (int i = 0; i < 4; ++i)
        a[i] = *(const f16x8*)&As[(wr * 64 + i * 16 + ln) * LDSP + ks * 32 + q8];
#pragma unroll
      for (int j = 0; j < 4; ++j)
        b[j] = *(const f16x8*)&Bs[(wc * 64 + j * 16 + ln) * LDSP + ks * 32 + q8];
#pragma unroll
      for (int i = 0; i < 4; ++i)
#pragma unroll
        for (int j = 0; j < 4; ++j)
          acc[i][j] = mfma_16x16x32(a[i], b[j], acc[i][j]);
    }
    __syncthreads();
  }

#pragma unroll
  for (int i = 0; i < 4; ++i) {
#pragma unroll
    for (int j = 0; j < 4; ++j) {
      int gc = n0 + wc * 64 + j * 16 + ln;
#pragma unroll
      for (int r = 0; r < 4; ++r) {
        long gr = m0 + wr * 64 + i * 16 + quad * 4 + r;
        float v = acc[i][j][r];
        if (FINAL)
          Cf[gr * NDIM + gc] = v + bias[gc];
        else
          Ch[gr * (long)NDIM + gc] = (f16)v;
      }
    }
  }
}

// ---------------- launch ----------------
extern "C" void kernel_launch(void* const* d_in, const int* in_sizes, int n_in,
                              void* d_out, int out_size, void* d_ws, size_t ws_size,
                              hipStream_t stream) {
  const float* x = (const float*)d_in[0];
  const float* qkv_w = (const float*)d_in[1];
  const float* proj_w = (const float*)d_in[2];
  const float* proj_b = (const float*)d_in[3];
  const float* lepe_w = (const float*)d_in[4];
  const float* lepe_b = (const float*)d_in[5];
  float* out = (float*)d_out;

  char* ws = (char*)d_ws;
  f16* w16 = (f16*)(ws + 0);           //    884,736 B
  f16* pw16 = (f16*)(ws + 884736);     //    294,912 B
  f16* afused = (f16*)(ws + 1179648);  // 50,331,648 B  (total ~51.5 MB)

  k_cvt<<<216, 256, 0, stream>>>(qkv_w, w16, 55296);
  k_cvt<<<72, 256, 0, stream>>>(proj_w, pw16, 18432);
  // fused lepe + qkv + attention -> afused
  k_fused<<<1024, 256, 0, stream>>>(x, w16, lepe_w, lepe_b, afused);
  // proj: [65536 x 384] @ [384 x 384]^T + bias -> out (fp32)
  k_gemm<384, true><<<512 * 3, 256, 0, stream>>>(afused, pw16, proj_b, nullptr, out);
}

// Round 3
// 491.761 us; speedup vs baseline: 1.2041x; 1.2041x over previous
//
#include <hip/hip_runtime.h>

// LePEAttention: B=16, H=W=64, C=384, HEADS=12, hd=32, IDX=0 (vertical strips).
// Pipeline: k_prep (cvt x->x16 + lepe) -> k_qkv (MFMA GEMM, strip-permuted store)
//           -> k_attn (block=strip, 4 waves x 3 heads) -> k_proj (+lepe +bias, fp32).
// MFMA layouts (HW-verified): A[m=lane&15][k=quad*8+j]; B mirrored;
//   C/D: col=lane&15, row=quad*4+reg.

typedef _Float16 f16;
typedef _Float16 f16x8 __attribute__((ext_vector_type(8)));
typedef float    f32x4 __attribute__((ext_vector_type(4)));

__device__ __forceinline__ f32x4 mfma_16x16x32(f16x8 a, f16x8 b, f32x4 c) {
  return __builtin_amdgcn_mfma_f32_16x16x32_f16(a, b, c, 0, 0, 0);
}

// async global->LDS 16B copy (dest must be wave-uniform base + lane*16)
__device__ __forceinline__ void gl_lds16(const f16* g, f16* l) {
  __builtin_amdgcn_global_load_lds((const __attribute__((address_space(1))) void*)g,
                                   (__attribute__((address_space(3))) void*)l, 16, 0, 0);
}

// ---------------- fp32 -> fp16 convert (weights) ----------------
__global__ __launch_bounds__(256) void k_cvt(const float* __restrict__ src,
                                             f16* __restrict__ dst, int n8) {
  int i = blockIdx.x * 256 + threadIdx.x;
  if (i >= n8) return;
  const f32x4* s4 = (const f32x4*)src;
  f32x4 a = s4[2 * i], b = s4[2 * i + 1];
  f16x8 o;
#pragma unroll
  for (int j = 0; j < 4; ++j) { o[j] = (f16)a[j]; o[4 + j] = (f16)b[j]; }
  *(f16x8*)&dst[(long)i * 8] = o;
}

// ---------------- fused cvt(x) + LePE conv ----------------
// thread = (token, c0 group of 8). Coalesced: 48 consecutive threads cover one
// token's 384 channels.
__global__ __launch_bounds__(256) void k_prep(const float* __restrict__ x,
                                              const float* __restrict__ lw,
                                              const float* __restrict__ lb,
                                              f16* __restrict__ x16,
                                              f16* __restrict__ lepe16) {
  __shared__ float ws[384 * 9];
  __shared__ float bs[384];
  for (int i = threadIdx.x; i < 384 * 9; i += 256) ws[i] = lw[i];
  for (int i = threadIdx.x; i < 384; i += 256) bs[i] = lb[i];
  __syncthreads();

  int chunk = blockIdx.x * 256 + threadIdx.x;
  int token = chunk / 48;
  int c0 = (chunk - token * 48) * 8;
  int b = token >> 12, n = token & 4095, h = n >> 6, w = n & 63;
  const float* xb = x + (long)(b << 12) * 384;

  float a8[8];
#pragma unroll
  for (int cc = 0; cc < 8; ++cc) a8[cc] = bs[c0 + cc];
  f16x8 cv;
#pragma unroll
  for (int ky = 0; ky < 3; ++ky) {
    int hh = h + ky - 1;
    if (hh < 0 || hh > 63) continue;
#pragma unroll
    for (int kx = 0; kx < 3; ++kx) {
      int ww = w + kx - 1;
      if (ww < 0 || ww > 63) continue;
      const float* p = xb + (long)((hh << 6) + ww) * 384 + c0;
      float4 u = *(const float4*)p;
      float4 v = *(const float4*)(p + 4);
      float xs[8] = {u.x, u.y, u.z, u.w, v.x, v.y, v.z, v.w};
      if (ky == 1 && kx == 1) {
#pragma unroll
        for (int cc = 0; cc < 8; ++cc) cv[cc] = (f16)xs[cc];
      }
#pragma unroll
      for (int cc = 0; cc < 8; ++cc)
        a8[cc] += xs[cc] * ws[(c0 + cc) * 9 + ky * 3 + kx];
    }
  }
  f16x8 o;
#pragma unroll
  for (int cc = 0; cc < 8; ++cc) o[cc] = (f16)a8[cc];
  *(f16x8*)&x16[(long)token * 384 + c0] = cv;
  *(f16x8*)&lepe16[(long)token * 384 + c0] = o;
}

// ---------------- QKV GEMM: qkv[perm(t)][1152] = x16 @ w16^T ----------------
// 128x128 tile, BK=64, global_load_lds staging w/ 16B xor swizzle, nt-major grid.
// Store row permutation t=(b,l*64+w) -> prow=(b,w*64+l) for contiguous strips.
__global__ __launch_bounds__(256) void k_qkv(const f16* __restrict__ A,
                                             const f16* __restrict__ Bt,
                                             f16* __restrict__ C) {
  __shared__ alignas(16) f16 As[128 * 64];
  __shared__ alignas(16) f16 Bs[128 * 64];
  const int tid = threadIdx.x;
  const int lane = tid & 63;
  const int wave = tid >> 6;
  const int wr = wave >> 1, wc = wave & 1;
  const int ln = lane & 15, quad = lane >> 4, q8 = quad * 8;
  const int mt = blockIdx.x & 511;   // nt-major: consecutive blocks share B-tile,
  const int nt = blockIdx.x >> 9;    // A fetched ~once (L3-resident x16)
  const long m0 = (long)mt * 128;
  const int n0 = nt * 128;

  f32x4 acc[4][4] = {};
  for (int k0 = 0; k0 < 384; k0 += 64) {
#pragma unroll
    for (int r = 0; r < 4; ++r) {
      int flat = r * 256 + tid;
      int row = flat >> 3, c8 = flat & 7;
      int sc8 = (c8 ^ (row & 7)) * 8;
      gl_lds16(&A[(m0 + row) * 384 + k0 + sc8], &As[flat * 8]);
      gl_lds16(&Bt[(long)(n0 + row) * 384 + k0 + sc8], &Bs[flat * 8]);
    }
    __syncthreads();
#pragma unroll
    for (int ks = 0; ks < 2; ++ks) {
      f16x8 a[4], b[4];
#pragma unroll
      for (int i = 0; i < 4; ++i)
        a[i] = *(const f16x8*)&As[(wr * 64 + i * 16 + ln) * 64 +
                                  ((ks * 4 + quad) ^ (ln & 7)) * 8];
#pragma unroll
      for (int j = 0; j < 4; ++j)
        b[j] = *(const f16x8*)&Bs[(wc * 64 + j * 16 + ln) * 64 +
                                  ((ks * 4 + quad) ^ (ln & 7)) * 8];
#pragma unroll
      for (int i = 0; i < 4; ++i)
#pragma unroll
        for (int j = 0; j < 4; ++j)
          acc[i][j] = mfma_16x16x32(a[i], b[j], acc[i][j]);
    }
    __syncthreads();
  }

#pragma unroll
  for (int i = 0; i < 4; ++i)
#pragma unroll
    for (int j = 0; j < 4; ++j) {
      int gc = n0 + wc * 64 + j * 16 + ln;
#pragma unroll
      for (int r = 0; r < 4; ++r) {
        int t = (int)m0 + wr * 64 + i * 16 + quad * 4 + r;
        int nn = t & 4095;
        long prow = (long)(t & ~4095) + ((nn & 63) << 6) + (nn >> 6);
        C[prow * 1152 + gc] = (f16)acc[i][j][r];
      }
    }
}

// ---------------- attention: block = strip, 4 waves x 3 heads ----------------
// qkv rows are strip-contiguous. Pure store to attnout (lepe added in proj).
__global__ __launch_bounds__(256) void k_attn(const f16* __restrict__ qkv,
                                              f16* __restrict__ attnout) {
  // per-wave LDS (halfs): qs@0 (64x40), ks@2560 (64x40), vt@5120 (32x72).
  // ps (64x72=4608) overlays qs+ks; obuf (64x40) overlays ps. total 7424 h/wave.
  __shared__ alignas(16) f16 shp[4][7424];
  const int lane = threadIdx.x & 63;
  const int wave = threadIdx.x >> 6;
  const int ln = lane & 15, quad = lane >> 4, q8 = quad * 8;
  const int b = blockIdx.x >> 6, w = blockIdx.x & 63;
  const long sbase = (long)b * 4096 + (long)w * 64;  // first permuted row of strip

  f16* qs = shp[wave];
  f16* ks = shp[wave] + 2560;
  f16* vt = shp[wave] + 5120;
  f16* ps = shp[wave];
  f16* obuf = shp[wave];
  const float qscale = 0.17677669529663687f;  // 32^-0.5

  for (int hi = 0; hi < 3; ++hi) {
    const int hh = wave * 3 + hi;
    // load q,k,v (64 tokens x 32 halfs each); rows stride 2304 B, 64 B used
#pragma unroll
    for (int r = 0; r < 4; ++r) {
      int flat = r * 64 + lane;
      int l = flat >> 2, dg = (flat & 3) * 8;
      long ta = (sbase + l) * 1152 + hh * 32 + dg;
      f16x8 qv = *(const f16x8*)&qkv[ta];
      f16x8 kv = *(const f16x8*)&qkv[ta + 384];
      f16x8 vv = *(const f16x8*)&qkv[ta + 768];
      // pre-scale q by 1/sqrt(hd)
#pragma unroll
      for (int ii = 0; ii < 8; ++ii) qv[ii] = (f16)((float)qv[ii] * qscale);
      *(f16x8*)&qs[l * 40 + dg] = qv;
      *(f16x8*)&ks[l * 40 + dg] = kv;
#pragma unroll
      for (int ii = 0; ii < 8; ++ii) vt[(dg + ii) * 72 + l] = vv[ii];
    }
    // S = Q K^T (64x64, K=32)
    f16x8 aq[4], bk[4];
#pragma unroll
    for (int i = 0; i < 4; ++i) aq[i] = *(const f16x8*)&qs[(i * 16 + ln) * 40 + q8];
#pragma unroll
    for (int j = 0; j < 4; ++j) bk[j] = *(const f16x8*)&ks[(j * 16 + ln) * 40 + q8];
    f32x4 sc[4][4] = {};
#pragma unroll
    for (int i = 0; i < 4; ++i)
#pragma unroll
      for (int j = 0; j < 4; ++j) sc[i][j] = mfma_16x16x32(aq[i], bk[j], sc[i][j]);

    // softmax rows; deferred normalization
    float rs[4][4];
#pragma unroll
    for (int i = 0; i < 4; ++i)
#pragma unroll
      for (int r = 0; r < 4; ++r) {
        float m = -1e30f;
#pragma unroll
        for (int j = 0; j < 4; ++j) m = fmaxf(m, sc[i][j][r]);
#pragma unroll
        for (int off = 1; off < 16; off <<= 1) m = fmaxf(m, __shfl_xor(m, off, 64));
        float sum = 0.f;
#pragma unroll
        for (int j = 0; j < 4; ++j) {
          float p = __expf(sc[i][j][r] - m);
          sc[i][j][r] = p;
          sum += p;
        }
#pragma unroll
        for (int off = 1; off < 16; off <<= 1) sum += __shfl_xor(sum, off, 64);
        rs[i][r] = 1.0f / sum;
      }

    // P -> ps (overlays qs/ks; same-wave in-order DS after aq/bk reads)
#pragma unroll
    for (int i = 0; i < 4; ++i)
#pragma unroll
      for (int j = 0; j < 4; ++j)
#pragma unroll
        for (int r = 0; r < 4; ++r)
          ps[(i * 16 + quad * 4 + r) * 72 + j * 16 + ln] = (f16)sc[i][j][r];

    // O = P V (64x32, K=64)
    f32x4 oc[4][2] = {};
#pragma unroll
    for (int k2 = 0; k2 < 2; ++k2) {
      f16x8 ap[4], bv[2];
#pragma unroll
      for (int i = 0; i < 4; ++i)
        ap[i] = *(const f16x8*)&ps[(i * 16 + ln) * 72 + k2 * 32 + q8];
#pragma unroll
      for (int j = 0; j < 2; ++j)
        bv[j] = *(const f16x8*)&vt[(j * 16 + ln) * 72 + k2 * 32 + q8];
#pragma unroll
      for (int i = 0; i < 4; ++i)
#pragma unroll
        for (int j = 0; j < 2; ++j) oc[i][j] = mfma_16x16x32(ap[i], bv[j], oc[i][j]);
    }

    // normalize -> obuf (overlays ps; reads done) -> vectorized store
#pragma unroll
    for (int i = 0; i < 4; ++i)
#pragma unroll
      for (int j = 0; j < 2; ++j)
#pragma unroll
        for (int r = 0; r < 4; ++r)
          obuf[(i * 16 + quad * 4 + r) * 40 + j * 16 + ln] =
              (f16)(oc[i][j][r] * rs[i][r]);
    {
      int row = lane >> 1, hf = lane & 1;
#pragma unroll
      for (int rr = 0; rr < 2; ++rr) {
        int rw = rr * 32 + row;
        const f16* ob = &obuf[rw * 40 + hf * 16];
        f16x8 o0 = *(const f16x8*)ob;
        f16x8 o1 = *(const f16x8*)(ob + 8);
        f16* gp = attnout + (sbase + rw) * 384 + hh * 32 + hf * 16;
        *(f16x8*)gp = o0;
        *(f16x8*)(gp + 8) = o1;
      }
    }
  }
}

// ---------------- proj GEMM: out = (attn + lepe) @ pw^T + bias (fp32) ----------------
__global__ __launch_bounds__(256) void k_proj(const f16* __restrict__ A1,
                                              const f16* __restrict__ A2,
                                              const f16* __restrict__ Bt,
                                              const float* __restrict__ bias,
                                              float* __restrict__ Cf) {
  __shared__ alignas(16) f16 As[128 * 64];
  __shared__ alignas(16) f16 Bs[128 * 64];
  const int tid = threadIdx.x;
  const int lane = tid & 63;
  const int wave = tid >> 6;
  const int wr = wave >> 1, wc = wave & 1;
  const int ln = lane & 15, quad = lane >> 4, q8 = quad * 8;
  const int mt = blockIdx.x & 511;
  const int nt = blockIdx.x >> 9;
  const long m0 = (long)mt * 128;
  const int n0 = nt * 128;

  f32x4 acc[4][4] = {};
  for (int k0 = 0; k0 < 384; k0 += 64) {
#pragma unroll
    for (int r = 0; r < 4; ++r) {
      int flat = r * 256 + tid;
      int row = flat >> 3, c8 = flat & 7;
      int sc8 = (c8 ^ (row & 7)) * 8;
      long ai = (m0 + row) * 384 + k0 + sc8;
      f16x8 s = *(const f16x8*)&A1[ai] + *(const f16x8*)&A2[ai];
      *(f16x8*)&As[flat * 8] = s;
      gl_lds16(&Bt[(long)(n0 + row) * 384 + k0 + sc8], &Bs[flat * 8]);
    }
    __syncthreads();
#pragma unroll
    for (int ks = 0; ks < 2; ++ks) {
      f16x8 a[4], b[4];
#pragma unroll
      for (int i = 0; i < 4; ++i)
        a[i] = *(const f16x8*)&As[(wr * 64 + i * 16 + ln) * 64 +
                                  ((ks * 4 + quad) ^ (ln & 7)) * 8];
#pragma unroll
      for (int j = 0; j < 4; ++j)
        b[j] = *(const f16x8*)&Bs[(wc * 64 + j * 16 + ln) * 64 +
                                  ((ks * 4 + quad) ^ (ln & 7)) * 8];
#pragma unroll
      for (int i = 0; i < 4; ++i)
#pragma unroll
        for (int j = 0; j < 4; ++j)
          acc[i][j] = mfma_16x16x32(a[i], b[j], acc[i][j]);
    }
    __syncthreads();
  }

#pragma unroll
  for (int i = 0; i < 4; ++i)
#pragma unroll
    for (int j = 0; j < 4; ++j) {
      int gc = n0 + wc * 64 + j * 16 + ln;
#pragma unroll
      for (int r = 0; r < 4; ++r) {
        long gr = m0 + wr * 64 + i * 16 + quad * 4 + r;
        Cf[gr * 384 + gc] = acc[i][j][r] + bias[gc];
      }
    }
}

// ---------------- launch ----------------
extern "C" void kernel_launch(void* const* d_in, const int* in_sizes, int n_in,
                              void* d_out, int out_size, void* d_ws, size_t ws_size,
                              hipStream_t stream) {
  const float* x = (const float*)d_in[0];
  const float* qkv_w = (const float*)d_in[1];
  const float* proj_w = (const float*)d_in[2];
  const float* proj_b = (const float*)d_in[3];
  const float* lepe_w = (const float*)d_in[4];
  const float* lepe_b = (const float*)d_in[5];
  float* out = (float*)d_out;

  char* ws = (char*)d_ws;
  f16* w16 = (f16*)(ws + 0);              //     884,736 B
  f16* pw16 = (f16*)(ws + 884736);        //     294,912 B
  f16* x16 = (f16*)(ws + 1179648);        //  50,331,648 B (dead after k_qkv)
  f16* attnout = x16;                     //  reuses x16 region
  f16* lepe16 = (f16*)(ws + 51511296);    //  50,331,648 B
  f16* qkv16 = (f16*)(ws + 101842944);    // 150,994,944 B  (total 252,837,888 B)

  k_cvt<<<216, 256, 0, stream>>>(qkv_w, w16, 55296);
  k_cvt<<<72, 256, 0, stream>>>(proj_w, pw16, 18432);
  k_prep<<<12288, 256, 0, stream>>>(x, lepe_w, lepe_b, x16, lepe16);
  k_qkv<<<512 * 9, 256, 0, stream>>>(x16, w16, qkv16);
  k_attn<<<1024, 256, 0, stream>>>(qkv16, attnout);
  k_proj<<<512 * 3, 256, 0, stream>>>(attnout, lepe16, pw16, proj_b, out);
}

// Round 4
// 468.224 us; speedup vs baseline: 1.2647x; 1.0503x over previous
//
#include <hip/hip_runtime.h>

// LePEAttention: B=16, H=W=64, C=384, HEADS=12, hd=32, IDX=0 (vertical strips).
// Pipeline: k_prep (cvt x->x16 + lepe) -> k_qkv (MFMA GEMM, strip-permuted store)
//           -> k_attn (block=strip, 4 waves x 3 heads) -> k_proj (+lepe +bias, fp32).
// MFMA layouts (HW-verified): A[m=lane&15][k=quad*8+j]; B mirrored;
//   C/D: col=lane&15, row=quad*4+reg.
// R4 change: k_prep LDS weight layout interleaved [tap][c&7][c>>3] -> stride-1
// lane index, kills the 48.9M 16-way bank conflicts measured in R3.

typedef _Float16 f16;
typedef _Float16 f16x8 __attribute__((ext_vector_type(8)));
typedef float    f32x4 __attribute__((ext_vector_type(4)));

__device__ __forceinline__ f32x4 mfma_16x16x32(f16x8 a, f16x8 b, f32x4 c) {
  return __builtin_amdgcn_mfma_f32_16x16x32_f16(a, b, c, 0, 0, 0);
}

// async global->LDS 16B copy (dest must be wave-uniform base + lane*16)
__device__ __forceinline__ void gl_lds16(const f16* g, f16* l) {
  __builtin_amdgcn_global_load_lds((const __attribute__((address_space(1))) void*)g,
                                   (__attribute__((address_space(3))) void*)l, 16, 0, 0);
}

// ---------------- fp32 -> fp16 convert (weights) ----------------
__global__ __launch_bounds__(256) void k_cvt(const float* __restrict__ src,
                                             f16* __restrict__ dst, int n8) {
  int i = blockIdx.x * 256 + threadIdx.x;
  if (i >= n8) return;
  const f32x4* s4 = (const f32x4*)src;
  f32x4 a = s4[2 * i], b = s4[2 * i + 1];
  f16x8 o;
#pragma unroll
  for (int j = 0; j < 4; ++j) { o[j] = (f16)a[j]; o[4 + j] = (f16)b[j]; }
  *(f16x8*)&dst[(long)i * 8] = o;
}

// ---------------- fused cvt(x) + LePE conv ----------------
// thread = (token, c0 group of 8). Coalesced: 48 consecutive threads cover one
// token's 384 channels. LDS weights interleaved: ws[tap*384 + (c&7)*48 + (c>>3)]
// so the lane-varying part (c0>>3, 0..47) has bank stride 1 -> conflict-free.
__global__ __launch_bounds__(256) void k_prep(const float* __restrict__ x,
                                              const float* __restrict__ lw,
                                              const float* __restrict__ lb,
                                              f16* __restrict__ x16,
                                              f16* __restrict__ lepe16) {
  __shared__ float ws[9 * 384];
  __shared__ float bs[384];
  for (int i = threadIdx.x; i < 3456; i += 256) {
    int c = i / 9, tap = i - c * 9;
    ws[tap * 384 + (c & 7) * 48 + (c >> 3)] = lw[i];
  }
  for (int i = threadIdx.x; i < 384; i += 256)
    bs[(i & 7) * 48 + (i >> 3)] = lb[i];
  __syncthreads();

  int chunk = blockIdx.x * 256 + threadIdx.x;
  int token = chunk / 48;
  int c0 = (chunk - token * 48) * 8;
  int cg = c0 >> 3;  // 0..47, stride-1 across lanes
  int b = token >> 12, n = token & 4095, h = n >> 6, w = n & 63;
  const float* xb = x + (long)(b << 12) * 384;

  float a8[8];
#pragma unroll
  for (int cc = 0; cc < 8; ++cc) a8[cc] = bs[cc * 48 + cg];
  f16x8 cv;
#pragma unroll
  for (int ky = 0; ky < 3; ++ky) {
    int hh = h + ky - 1;
    if (hh < 0 || hh > 63) continue;
#pragma unroll
    for (int kx = 0; kx < 3; ++kx) {
      int ww = w + kx - 1;
      if (ww < 0 || ww > 63) continue;
      const float* p = xb + (long)((hh << 6) + ww) * 384 + c0;
      float4 u = *(const float4*)p;
      float4 v = *(const float4*)(p + 4);
      float xs[8] = {u.x, u.y, u.z, u.w, v.x, v.y, v.z, v.w};
      if (ky == 1 && kx == 1) {
#pragma unroll
        for (int cc = 0; cc < 8; ++cc) cv[cc] = (f16)xs[cc];
      }
      int tap = ky * 3 + kx;
#pragma unroll
      for (int cc = 0; cc < 8; ++cc)
        a8[cc] += xs[cc] * ws[tap * 384 + cc * 48 + cg];
    }
  }
  f16x8 o;
#pragma unroll
  for (int cc = 0; cc < 8; ++cc) o[cc] = (f16)a8[cc];
  *(f16x8*)&x16[(long)token * 384 + c0] = cv;
  *(f16x8*)&lepe16[(long)token * 384 + c0] = o;
}

// ---------------- QKV GEMM: qkv[perm(t)][1152] = x16 @ w16^T ----------------
// 128x128 tile, BK=64, global_load_lds staging w/ 16B xor swizzle, nt-major grid.
// Store row permutation t=(b,l*64+w) -> prow=(b,w*64+l) for contiguous strips.
__global__ __launch_bounds__(256) void k_qkv(const f16* __restrict__ A,
                                             const f16* __restrict__ Bt,
                                             f16* __restrict__ C) {
  __shared__ alignas(16) f16 As[128 * 64];
  __shared__ alignas(16) f16 Bs[128 * 64];
  const int tid = threadIdx.x;
  const int lane = tid & 63;
  const int wave = tid >> 6;
  const int wr = wave >> 1, wc = wave & 1;
  const int ln = lane & 15, quad = lane >> 4, q8 = quad * 8;
  const int mt = blockIdx.x & 511;   // nt-major: consecutive blocks share B-tile,
  const int nt = blockIdx.x >> 9;    // A fetched ~once (L3-resident x16)
  const long m0 = (long)mt * 128;
  const int n0 = nt * 128;

  f32x4 acc[4][4] = {};
  for (int k0 = 0; k0 < 384; k0 += 64) {
#pragma unroll
    for (int r = 0; r < 4; ++r) {
      int flat = r * 256 + tid;
      int row = flat >> 3, c8 = flat & 7;
      int sc8 = (c8 ^ (row & 7)) * 8;
      gl_lds16(&A[(m0 + row) * 384 + k0 + sc8], &As[flat * 8]);
      gl_lds16(&Bt[(long)(n0 + row) * 384 + k0 + sc8], &Bs[flat * 8]);
    }
    __syncthreads();
#pragma unroll
    for (int ks = 0; ks < 2; ++ks) {
      f16x8 a[4], b[4];
#pragma unroll
      for (int i = 0; i < 4; ++i)
        a[i] = *(const f16x8*)&As[(wr * 64 + i * 16 + ln) * 64 +
                                  ((ks * 4 + quad) ^ (ln & 7)) * 8];
#pragma unroll
      for (int j = 0; j < 4; ++j)
        b[j] = *(const f16x8*)&Bs[(wc * 64 + j * 16 + ln) * 64 +
                                  ((ks * 4 + quad) ^ (ln & 7)) * 8];
#pragma unroll
      for (int i = 0; i < 4; ++i)
#pragma unroll
        for (int j = 0; j < 4; ++j)
          acc[i][j] = mfma_16x16x32(a[i], b[j], acc[i][j]);
    }
    __syncthreads();
  }

#pragma unroll
  for (int i = 0; i < 4; ++i)
#pragma unroll
    for (int j = 0; j < 4; ++j) {
      int gc = n0 + wc * 64 + j * 16 + ln;
#pragma unroll
      for (int r = 0; r < 4; ++r) {
        int t = (int)m0 + wr * 64 + i * 16 + quad * 4 + r;
        int nn = t & 4095;
        long prow = (long)(t & ~4095) + ((nn & 63) << 6) + (nn >> 6);
        C[prow * 1152 + gc] = (f16)acc[i][j][r];
      }
    }
}

// ---------------- attention: block = strip, 4 waves x 3 heads ----------------
// qkv rows are strip-contiguous. Pure store to attnout (lepe added in proj).
__global__ __launch_bounds__(256) void k_attn(const f16* __restrict__ qkv,
                                              f16* __restrict__ attnout) {
  // per-wave LDS (halfs): qs@0 (64x40), ks@2560 (64x40), vt@5120 (32x72).
  // ps (64x72=4608) overlays qs+ks; obuf (64x40) overlays ps. total 7424 h/wave.
  __shared__ alignas(16) f16 shp[4][7424];
  const int lane = threadIdx.x & 63;
  const int wave = threadIdx.x >> 6;
  const int ln = lane & 15, quad = lane >> 4, q8 = quad * 8;
  const int b = blockIdx.x >> 6, w = blockIdx.x & 63;
  const long sbase = (long)b * 4096 + (long)w * 64;  // first permuted row of strip

  f16* qs = shp[wave];
  f16* ks = shp[wave] + 2560;
  f16* vt = shp[wave] + 5120;
  f16* ps = shp[wave];
  f16* obuf = shp[wave];
  const float qscale = 0.17677669529663687f;  // 32^-0.5

  for (int hi = 0; hi < 3; ++hi) {
    const int hh = wave * 3 + hi;
    // load q,k,v (64 tokens x 32 halfs each); rows stride 2304 B, 64 B used
#pragma unroll
    for (int r = 0; r < 4; ++r) {
      int flat = r * 64 + lane;
      int l = flat >> 2, dg = (flat & 3) * 8;
      long ta = (sbase + l) * 1152 + hh * 32 + dg;
      f16x8 qv = *(const f16x8*)&qkv[ta];
      f16x8 kv = *(const f16x8*)&qkv[ta + 384];
      f16x8 vv = *(const f16x8*)&qkv[ta + 768];
      // pre-scale q by 1/sqrt(hd)
#pragma unroll
      for (int ii = 0; ii < 8; ++ii) qv[ii] = (f16)((float)qv[ii] * qscale);
      *(f16x8*)&qs[l * 40 + dg] = qv;
      *(f16x8*)&ks[l * 40 + dg] = kv;
#pragma unroll
      for (int ii = 0; ii < 8; ++ii) vt[(dg + ii) * 72 + l] = vv[ii];
    }
    // S = Q K^T (64x64, K=32)
    f16x8 aq[4], bk[4];
#pragma unroll
    for (int i = 0; i < 4; ++i) aq[i] = *(const f16x8*)&qs[(i * 16 + ln) * 40 + q8];
#pragma unroll
    for (int j = 0; j < 4; ++j) bk[j] = *(const f16x8*)&ks[(j * 16 + ln) * 40 + q8];
    f32x4 sc[4][4] = {};
#pragma unroll
    for (int i = 0; i < 4; ++i)
#pragma unroll
      for (int j = 0; j < 4; ++j) sc[i][j] = mfma_16x16x32(aq[i], bk[j], sc[i][j]);

    // softmax rows; deferred normalization
    float rs[4][4];
#pragma unroll
    for (int i = 0; i < 4; ++i)
#pragma unroll
      for (int r = 0; r < 4; ++r) {
        float m = -1e30f;
#pragma unroll
        for (int j = 0; j < 4; ++j) m = fmaxf(m, sc[i][j][r]);
#pragma unroll
        for (int off = 1; off < 16; off <<= 1) m = fmaxf(m, __shfl_xor(m, off, 64));
        float sum = 0.f;
#pragma unroll
        for (int j = 0; j < 4; ++j) {
          float p = __expf(sc[i][j][r] - m);
          sc[i][j][r] = p;
          sum += p;
        }
#pragma unroll
        for (int off = 1; off < 16; off <<= 1) sum += __shfl_xor(sum, off, 64);
        rs[i][r] = 1.0f / sum;
      }

    // P -> ps (overlays qs/ks; same-wave in-order DS after aq/bk reads)
#pragma unroll
    for (int i = 0; i < 4; ++i)
#pragma unroll
      for (int j = 0; j < 4; ++j)
#pragma unroll
        for (int r = 0; r < 4; ++r)
          ps[(i * 16 + quad * 4 + r) * 72 + j * 16 + ln] = (f16)sc[i][j][r];

    // O = P V (64x32, K=64)
    f32x4 oc[4][2] = {};
#pragma unroll
    for (int k2 = 0; k2 < 2; ++k2) {
      f16x8 ap[4], bv[2];
#pragma unroll
      for (int i = 0; i < 4; ++i)
        ap[i] = *(const f16x8*)&ps[(i * 16 + ln) * 72 + k2 * 32 + q8];
#pragma unroll
      for (int j = 0; j < 2; ++j)
        bv[j] = *(const f16x8*)&vt[(j * 16 + ln) * 72 + k2 * 32 + q8];
#pragma unroll
      for (int i = 0; i < 4; ++i)
#pragma unroll
        for (int j = 0; j < 2; ++j) oc[i][j] = mfma_16x16x32(ap[i], bv[j], oc[i][j]);
    }

    // normalize -> obuf (overlays ps; reads done) -> vectorized store
#pragma unroll
    for (int i = 0; i < 4; ++i)
#pragma unroll
      for (int j = 0; j < 2; ++j)
#pragma unroll
        for (int r = 0; r < 4; ++r)
          obuf[(i * 16 + quad * 4 + r) * 40 + j * 16 + ln] =
              (f16)(oc[i][j][r] * rs[i][r]);
    {
      int row = lane >> 1, hf = lane & 1;
#pragma unroll
      for (int rr = 0; rr < 2; ++rr) {
        int rw = rr * 32 + row;
        const f16* ob = &obuf[rw * 40 + hf * 16];
        f16x8 o0 = *(const f16x8*)ob;
        f16x8 o1 = *(const f16x8*)(ob + 8);
        f16* gp = attnout + (sbase + rw) * 384 + hh * 32 + hf * 16;
        *(f16x8*)gp = o0;
        *(f16x8*)(gp + 8) = o1;
      }
    }
  }
}

// ---------------- proj GEMM: out = (attn + lepe) @ pw^T + bias (fp32) ----------------
__global__ __launch_bounds__(256) void k_proj(const f16* __restrict__ A1,
                                              const f16* __restrict__ A2,
                                              const f16* __restrict__ Bt,
                                              const float* __restrict__ bias,
                                              float* __restrict__ Cf) {
  __shared__ alignas(16) f16 As[128 * 64];
  __shared__ alignas(16) f16 Bs[128 * 64];
  const int tid = threadIdx.x;
  const int lane = tid & 63;
  const int wave = tid >> 6;
  const int wr = wave >> 1, wc = wave & 1;
  const int ln = lane & 15, quad = lane >> 4, q8 = quad * 8;
  const int mt = blockIdx.x & 511;
  const int nt = blockIdx.x >> 9;
  const long m0 = (long)mt * 128;
  const int n0 = nt * 128;

  f32x4 acc[4][4] = {};
  for (int k0 = 0; k0 < 384; k0 += 64) {
#pragma unroll
    for (int r = 0; r < 4; ++r) {
      int flat = r * 256 + tid;
      int row = flat >> 3, c8 = flat & 7;
      int sc8 = (c8 ^ (row & 7)) * 8;
      long ai = (m0 + row) * 384 + k0 + sc8;
      f16x8 s = *(const f16x8*)&A1[ai] + *(const f16x8*)&A2[ai];
      *(f16x8*)&As[flat * 8] = s;
      gl_lds16(&Bt[(long)(n0 + row) * 384 + k0 + sc8], &Bs[flat * 8]);
    }
    __syncthreads();
#pragma unroll
    for (int ks = 0; ks < 2; ++ks) {
      f16x8 a[4], b[4];
#pragma unroll
      for (int i = 0; i < 4; ++i)
        a[i] = *(const f16x8*)&As[(wr * 64 + i * 16 + ln) * 64 +
                                  ((ks * 4 + quad) ^ (ln & 7)) * 8];
#pragma unroll
      for (int j = 0; j < 4; ++j)
        b[j] = *(const f16x8*)&Bs[(wc * 64 + j * 16 + ln) * 64 +
                                  ((ks * 4 + quad) ^ (ln & 7)) * 8];
#pragma unroll
      for (int i = 0; i < 4; ++i)
#pragma unroll
        for (int j = 0; j < 4; ++j)
          acc[i][j] = mfma_16x16x32(a[i], b[j], acc[i][j]);
    }
    __syncthreads();
  }

#pragma unroll
  for (int i = 0; i < 4; ++i)
#pragma unroll
    for (int j = 0; j < 4; ++j) {
      int gc = n0 + wc * 64 + j * 16 + ln;
#pragma unroll
      for (int r = 0; r < 4; ++r) {
        long gr = m0 + wr * 64 + i * 16 + quad * 4 + r;
        Cf[gr * 384 + gc] = acc[i][j][r] + bias[gc];
      }
    }
}

// ---------------- launch ----------------
extern "C" void kernel_launch(void* const* d_in, const int* in_sizes, int n_in,
                              void* d_out, int out_size, void* d_ws, size_t ws_size,
                              hipStream_t stream) {
  const float* x = (const float*)d_in[0];
  const float* qkv_w = (const float*)d_in[1];
  const float* proj_w = (const float*)d_in[2];
  const float* proj_b = (const float*)d_in[3];
  const float* lepe_w = (const float*)d_in[4];
  const float* lepe_b = (const float*)d_in[5];
  float* out = (float*)d_out;

  char* ws = (char*)d_ws;
  f16* w16 = (f16*)(ws + 0);              //     884,736 B
  f16* pw16 = (f16*)(ws + 884736);        //     294,912 B
  f16* x16 = (f16*)(ws + 1179648);        //  50,331,648 B (dead after k_qkv)
  f16* attnout = x16;                     //  reuses x16 region
  f16* lepe16 = (f16*)(ws + 51511296);    //  50,331,648 B
  f16* qkv16 = (f16*)(ws + 101842944);    // 150,994,944 B  (total 252,837,888 B)

  k_cvt<<<216, 256, 0, stream>>>(qkv_w, w16, 55296);
  k_cvt<<<72, 256, 0, stream>>>(proj_w, pw16, 18432);
  k_prep<<<12288, 256, 0, stream>>>(x, lepe_w, lepe_b, x16, lepe16);
  k_qkv<<<512 * 9, 256, 0, stream>>>(x16, w16, qkv16);
  k_attn<<<1024, 256, 0, stream>>>(qkv16, attnout);
  k_proj<<<512 * 3, 256, 0, stream>>>(attnout, lepe16, pw16, proj_b, out);
}